// Round 2
// baseline (749.781 us; speedup 1.0000x reference)
//
#include <hip/hip_runtime.h>

// NNConvCritic on MI355X (gfx950).
// Pipeline:
//  ws memset -> prep (W2'/W1 f16 fragment tables) -> stats (S=EA^T EA via MFMA)
//  -> node_init (aggr = x@root_w + bias) -> bn (scale/shift from moments)
//  -> edge_kernel (msg = (h (x) x) @ W2' as f16 MFMA, K=1024+16(b2), atomic scatter)
//  -> pool (segment mean via atomics) -> critic (per-graph block).

#define E_EDGES  800000
#define N_NODES  50000
#define G_GRAPHS 64

typedef _Float16 f16x2 __attribute__((ext_vector_type(2)));
typedef _Float16 f16x8 __attribute__((ext_vector_type(8)));
typedef __fp16   fp16x2 __attribute__((ext_vector_type(2)));
typedef float    f32x4 __attribute__((ext_vector_type(4)));
typedef unsigned u32x4 __attribute__((ext_vector_type(4)));

union H2U { f16x2 h; unsigned u; };
union F8U { f16x8 v; f16x2 h2[4]; u32x4 u4; };

__device__ __forceinline__ f16x2 pkrtz(float a, float b) {
  fp16x2 r = __builtin_amdgcn_cvt_pkrtz(a, b);
  return __builtin_bit_cast(f16x2, r);
}

// ---------------------------------------------------------------------------
// prep: build f16 B-fragment tables.
// Bbuf: W2' fragments, layout [s(0..32)][nt(0..1)][lane(64)][r(4)] u32 (half2).
//   For s<32:  B[k][n], k = s*32 + q*8 + j, n = nt*16 + nl,
//              W2'[K][o] = W2[K>>4][(K&15)*20 + o]   (K = c*16 + i)
//   s==32: the b2 row-trick: B = b2[(q*8+j)*20 + n] for q<2 else 0.
// Bw1: W1 fragments for the h-GEMM (K=16 zero-padded to 32):
//   [nt(0..3)][lane][r] u32, B[k][n] = W1[k*64 + n] for k<16 else 0.
// ---------------------------------------------------------------------------
__global__ __launch_bounds__(256) void prep_kernel(
    const float* __restrict__ W2, const float* __restrict__ b2,
    const float* __restrict__ W1, unsigned* __restrict__ Bbuf,
    unsigned* __restrict__ Bw1)
{
  int tid = threadIdx.x;
  for (int idx = tid; idx < 33 * 512; idx += 256) {
    int r = idx & 3, lane = (idx >> 2) & 63, nt = (idx >> 8) & 1, s = idx >> 9;
    int q = lane >> 4, nl = lane & 15, n = nt * 16 + nl;
    float v0 = 0.f, v1 = 0.f;
    if (n < 20) {
      if (s < 32) {
        int K0 = s * 32 + q * 8 + 2 * r;
        int K1 = K0 + 1;
        v0 = W2[(K0 >> 4) * 320 + (K0 & 15) * 20 + n];
        v1 = W2[(K1 >> 4) * 320 + (K1 & 15) * 20 + n];
      } else if (q < 2) {
        int i0 = q * 8 + 2 * r;
        v0 = b2[i0 * 20 + n];
        v1 = b2[(i0 + 1) * 20 + n];
      }
    }
    H2U pk; pk.h = pkrtz(v0, v1);
    Bbuf[idx] = pk.u;
  }
  for (int idx = tid; idx < 1024; idx += 256) {
    int r = idx & 3, lane = (idx >> 2) & 63, nt = idx >> 8;
    int q = lane >> 4, nl = lane & 15, n = nt * 16 + nl;
    int k0 = q * 8 + 2 * r;
    float v0 = (k0 < 16)     ? W1[k0 * 64 + n]       : 0.f;
    float v1 = (k0 + 1 < 16) ? W1[(k0 + 1) * 64 + n] : 0.f;
    H2U pk; pk.h = pkrtz(v0, v1);
    Bw1[idx] = pk.u;
  }
}

// ---------------------------------------------------------------------------
// stats: S = EA^T @ EA (16x16) and m = column sums of EA, one pass over
// edge_attr. A-frag == B-frag (same per-lane values), so mfma(a,a,acc) gives
// the symmetric second-moment matrix regardless of the exact K slot order.
// ---------------------------------------------------------------------------
__global__ __launch_bounds__(256) void stats_kernel(
    const float* __restrict__ ea, float* __restrict__ wsS,
    float* __restrict__ wsm)
{
  int lane = threadIdx.x & 63, wave = threadIdx.x >> 6;
  int nl = lane & 15, q = lane >> 4;
  int gw = blockIdx.x * 4 + wave;
  int stride = gridDim.x * 4;
  f32x4 acc = (f32x4){0.f, 0.f, 0.f, 0.f};
  float ms = 0.f;
  for (int c0 = gw; c0 < E_EDGES / 32; c0 += stride) {
    const float* p = ea + (size_t)(c0 * 32 + q * 8) * 16 + nl;
    float v0 = p[0],      v1 = p[16],     v2 = p[32],  v3 = p[48];
    float v4 = p[64],     v5 = p[80],     v6 = p[96],  v7 = p[112];
    ms += (v0 + v1) + (v2 + v3) + (v4 + v5) + (v6 + v7);
    F8U av;
    av.h2[0] = pkrtz(v0, v1); av.h2[1] = pkrtz(v2, v3);
    av.h2[2] = pkrtz(v4, v5); av.h2[3] = pkrtz(v6, v7);
    acc = __builtin_amdgcn_mfma_f32_16x16x32_f16(av.v, av.v, acc, 0, 0, 0);
  }
  ms += __shfl_xor(ms, 16, 64);
  ms += __shfl_xor(ms, 32, 64);
  if (q == 0) unsafeAtomicAdd(&wsm[nl], ms);
#pragma unroll
  for (int r = 0; r < 4; ++r)
    unsafeAtomicAdd(&wsS[(q * 4 + r) * 16 + nl], acc[r]);
}

// ---------------------------------------------------------------------------
// bn: per-channel scale/shift from moments.
// h = w.ea + b1;  mean = w.m/E + b1;  E[h^2] = w^T S w /E + 2 b1 (w.m/E) + b1^2
// edge_kernel computes hnb = w.ea (no bias), so shift folds b1 in.
// ---------------------------------------------------------------------------
__global__ void bn_kernel(const float* __restrict__ wsS,
                          const float* __restrict__ wsm,
                          const float* __restrict__ W1,
                          const float* __restrict__ b1,
                          const float* __restrict__ gamma,
                          const float* __restrict__ beta,
                          float* __restrict__ sc, float* __restrict__ sh)
{
  int c = threadIdx.x;  // 64 threads
  float w[16];
#pragma unroll
  for (int j = 0; j < 16; ++j) w[j] = W1[j * 64 + c];
  const float invE = 1.0f / (float)E_EDGES;
  float mw = 0.f;
#pragma unroll
  for (int j = 0; j < 16; ++j) mw += wsm[j] * w[j];
  mw *= invE;
  float qf = 0.f;
  for (int j = 0; j < 16; ++j) {
    float t = 0.f;
#pragma unroll
    for (int j2 = 0; j2 < 16; ++j2) t += wsS[j * 16 + j2] * w[j2];
    qf += w[j] * t;
  }
  qf *= invE;
  float b = b1[c];
  float meanH = mw + b;
  float eh2 = qf + 2.f * b * mw + b * b;
  float var = eh2 - meanH * meanH;
  float s = gamma[c] * rsqrtf(var + 1e-5f);
  sc[c] = s;
  sh[c] = beta[c] + (b - meanH) * s;
}

// ---------------------------------------------------------------------------
// node_init: aggr[n][o] = bias[o] + sum_i x[n][i] * root_w[i][o]
// ---------------------------------------------------------------------------
__global__ __launch_bounds__(256) void node_init_kernel(
    const float* __restrict__ x, const float* __restrict__ root_w,
    const float* __restrict__ bias, float* __restrict__ aggr)
{
  int n = blockIdx.x * 256 + threadIdx.x;
  if (n >= N_NODES) return;
  float xr[16];
  const f32x4* xp = (const f32x4*)(x + (size_t)n * 16);
#pragma unroll
  for (int k = 0; k < 4; ++k) *(f32x4*)&xr[k * 4] = xp[k];
  float o[20];
#pragma unroll
  for (int oo = 0; oo < 20; ++oo) {
    float acc = bias[oo];
#pragma unroll
    for (int i = 0; i < 16; ++i) acc += xr[i] * root_w[i * 20 + oo];
    o[oo] = acc;
  }
  f32x4* op = (f32x4*)(aggr + (size_t)n * 20);
#pragma unroll
  for (int k = 0; k < 5; ++k) op[k] = *(f32x4*)&o[k * 4];
}

// ---------------------------------------------------------------------------
// edge_kernel: the main fused pass.
// Block = 256 threads = 4 waves, 64 edges per block-iteration.
// Each wave: computes h (BN+ReLU, f16, packed-dup) for its 16-edge tile via a
// zero-padded 16x16x32 MFMA, writes to LDS; then all 4 waves run the main
// GEMM over their K-quarter (8 K-steps, B-fragments in 64 VGPRs) for all 4
// M-tiles; wave 3 adds the b2 extra K-step (A = x). Per-wave msg slices in
// LDS, summed in the scatter stage, atomically added to aggr[dst].
// ---------------------------------------------------------------------------
__global__ __launch_bounds__(256, 2) void edge_kernel(
    const float* __restrict__ x, const float* __restrict__ ea,
    const int* __restrict__ ei, const float* __restrict__ sc,
    const float* __restrict__ sh, const unsigned* __restrict__ Bbuf,
    const unsigned* __restrict__ Bw1v, float* __restrict__ aggr)
{
  __shared__ unsigned hh[4 * 64 * 17];     // [tile][channel][m(16) pad 17]
  __shared__ float msgbuf[4 * 1280];       // per-wave [64 edges][20]
  const int tid = threadIdx.x;
  const int lane = tid & 63, wave = tid >> 6;
  const int nl = lane & 15, q = lane >> 4;
  const int* srcp = ei;
  const int* dstp = ei + E_EDGES;

  // B fragments for this wave's K-quarter: s in [8*wave, 8*wave+8)
  F8U bb[8][2];
#pragma unroll
  for (int sl = 0; sl < 8; ++sl)
#pragma unroll
    for (int nt = 0; nt < 2; ++nt)
      bb[sl][nt].u4 =
          ((const u32x4*)Bbuf)[((wave * 8 + sl) * 2 + nt) * 64 + lane];
  F8U bx[2];
  if (wave == 3) {
    bx[0].u4 = ((const u32x4*)Bbuf)[(32 * 2 + 0) * 64 + lane];
    bx[1].u4 = ((const u32x4*)Bbuf)[(32 * 2 + 1) * 64 + lane];
  }
  F8U bw1[4];
#pragma unroll
  for (int nt = 0; nt < 4; ++nt)
    bw1[nt].u4 = ((const u32x4*)Bw1v)[nt * 64 + lane];
  float scv[4], shv[4];
#pragma unroll
  for (int nt = 0; nt < 4; ++nt) {
    scv[nt] = sc[nt * 16 + nl];
    shv[nt] = sh[nt * 16 + nl];
  }
  const int hbase = (16 * wave + (q >> 1)) * 17 + nl;
  const int i0 = (q & 1) * 8;

  for (int it = blockIdx.x; it < (E_EDGES / 64); it += gridDim.x) {
    const int base = it * 64;

    // ---- h-stage: wave computes h for its own 16-edge tile ----
    {
      const int e = base + wave * 16 + nl;
      F8U aEA;
      if (q < 2) {
        const float* p = ea + (size_t)e * 16 + q * 8;
        f32x4 u = *(const f32x4*)p;
        f32x4 v = *(const f32x4*)(p + 4);
        aEA.h2[0] = pkrtz(u[0], u[1]); aEA.h2[1] = pkrtz(u[2], u[3]);
        aEA.h2[2] = pkrtz(v[0], v[1]); aEA.h2[3] = pkrtz(v[2], v[3]);
      } else {
        aEA.u4 = (u32x4){0u, 0u, 0u, 0u};
      }
#pragma unroll
      for (int nt = 0; nt < 4; ++nt) {
        f32x4 hD = __builtin_amdgcn_mfma_f32_16x16x32_f16(
            aEA.v, bw1[nt].v, (f32x4){0.f, 0.f, 0.f, 0.f}, 0, 0, 0);
#pragma unroll
        for (int r = 0; r < 4; ++r) {
          float h = fmaxf(hD[r] * scv[nt] + shv[nt], 0.f);
          H2U pk; pk.h = pkrtz(h, h);  // packed-duplicated
          hh[(wave * 64 + nt * 16 + nl) * 17 + q * 4 + r] = pk.u;
        }
      }
    }

    // ---- x gather (registers, f16 packed) ----
    F8U xp[4];
#pragma unroll
    for (int t = 0; t < 4; ++t) {
      int srcT = srcp[base + t * 16 + nl];
      const float* p = x + (size_t)srcT * 16 + i0;
      f32x4 u = *(const f32x4*)p;
      f32x4 v = *(const f32x4*)(p + 4);
      xp[t].h2[0] = pkrtz(u[0], u[1]); xp[t].h2[1] = pkrtz(u[2], u[3]);
      xp[t].h2[2] = pkrtz(v[0], v[1]); xp[t].h2[3] = pkrtz(v[2], v[3]);
    }
    __syncthreads();

    // ---- main K-loop: A[m][K] = h[m][K>>4] * x[m][K&15] ----
    f32x4 acc[4][2];
#pragma unroll
    for (int t = 0; t < 4; ++t) {
      acc[t][0] = (f32x4){0.f, 0.f, 0.f, 0.f};
      acc[t][1] = (f32x4){0.f, 0.f, 0.f, 0.f};
    }
#pragma unroll
    for (int sl = 0; sl < 8; ++sl) {
#pragma unroll
      for (int t = 0; t < 4; ++t) {
        H2U hu; hu.u = hh[hbase + t * 1088 + sl * 34];
        F8U av;
        av.h2[0] = hu.h * xp[t].h2[0];
        av.h2[1] = hu.h * xp[t].h2[1];
        av.h2[2] = hu.h * xp[t].h2[2];
        av.h2[3] = hu.h * xp[t].h2[3];
        acc[t][0] = __builtin_amdgcn_mfma_f32_16x16x32_f16(
            av.v, bb[sl][0].v, acc[t][0], 0, 0, 0);
        acc[t][1] = __builtin_amdgcn_mfma_f32_16x16x32_f16(
            av.v, bb[sl][1].v, acc[t][1], 0, 0, 0);
      }
    }
    if (wave == 3) {  // b2 extra K-step: A = x (coefficient-1 trick)
#pragma unroll
      for (int t = 0; t < 4; ++t) {
        F8U av;
        if (q < 2) av = xp[t];
        else       av.u4 = (u32x4){0u, 0u, 0u, 0u};
        acc[t][0] = __builtin_amdgcn_mfma_f32_16x16x32_f16(
            av.v, bx[0].v, acc[t][0], 0, 0, 0);
        acc[t][1] = __builtin_amdgcn_mfma_f32_16x16x32_f16(
            av.v, bx[1].v, acc[t][1], 0, 0, 0);
      }
    }

    // ---- per-wave msg slices (C/D layout: col = nl, row = q*4+r) ----
    float* ms = msgbuf + wave * 1280;
#pragma unroll
    for (int t = 0; t < 4; ++t) {
#pragma unroll
      for (int r = 0; r < 4; ++r)
        ms[(t * 16 + q * 4 + r) * 20 + nl] = acc[t][0][r];
      if (nl < 4) {
#pragma unroll
        for (int r = 0; r < 4; ++r)
          ms[(t * 16 + q * 4 + r) * 20 + 16 + nl] = acc[t][1][r];
      }
    }
    __syncthreads();

    // ---- scatter: sum 4 wave slices, atomicAdd to aggr[dst] ----
#pragma unroll
    for (int k2 = 0; k2 < 5; ++k2) {
      int v = tid + k2 * 256;
      int edl = v / 20, o = v - edl * 20;
      float val = msgbuf[v] + msgbuf[1280 + v] + msgbuf[2560 + v] +
                  msgbuf[3840 + v];
      int d = dstp[base + edl];
      unsafeAtomicAdd(&aggr[(size_t)d * 20 + o], val);
    }
    __syncthreads();
  }
}

// ---------------------------------------------------------------------------
// pool: segment sums + counts per graph (batch is sorted; contention per
// address ~780 serialized hardware f32 atomics -> ~1 us)
// ---------------------------------------------------------------------------
__global__ __launch_bounds__(256) void pool_kernel(
    const float* __restrict__ aggr, const int* __restrict__ batch,
    float* __restrict__ sums, float* __restrict__ cnt)
{
  int n = blockIdx.x * 256 + threadIdx.x;
  if (n >= N_NODES) return;
  int g = batch[n];
  const float* row = aggr + (size_t)n * 20;
#pragma unroll
  for (int o = 0; o < 20; ++o) unsafeAtomicAdd(&sums[g * 20 + o], row[o]);
  unsafeAtomicAdd(&cnt[g], 1.0f);
}

// ---------------------------------------------------------------------------
// critic: one block per graph. z = relu([pooled, a] @ Wc1 + bc1); out = z@Wc2+bc2
// ---------------------------------------------------------------------------
__global__ __launch_bounds__(256) void critic_kernel(
    const float* __restrict__ sums, const float* __restrict__ cnt,
    const float* __restrict__ a, const float* __restrict__ Wc1,
    const float* __restrict__ bc1, const float* __restrict__ Wc2,
    const float* __restrict__ bc2, float* __restrict__ out)
{
  int g = blockIdx.x, t = threadIdx.x;
  float invc = 1.f / fmaxf(cnt[g], 1.f);
  float z = bc1[t];
#pragma unroll
  for (int j = 0; j < 20; ++j)
    z += (sums[g * 20 + j] * invc) * Wc1[j * 256 + t];
#pragma unroll
  for (int j = 0; j < 8; ++j)
    z += a[g * 8 + j] * Wc1[(20 + j) * 256 + t];
  z = fmaxf(z, 0.f);
  float p = z * Wc2[t];
#pragma unroll
  for (int off = 32; off >= 1; off >>= 1) p += __shfl_down(p, off, 64);
  __shared__ float red[4];
  if ((t & 63) == 0) red[t >> 6] = p;
  __syncthreads();
  if (t == 0) out[g] = red[0] + red[1] + red[2] + red[3] + bc2[0];
}

// ---------------------------------------------------------------------------
extern "C" void kernel_launch(void* const* d_in, const int* in_sizes, int n_in,
                              void* d_out, int out_size, void* d_ws,
                              size_t ws_size, hipStream_t stream) {
  const float* x         = (const float*)d_in[0];
  const float* edge_attr = (const float*)d_in[1];
  const float* a         = (const float*)d_in[2];
  const int*   ei        = (const int*)d_in[3];
  const int*   batch     = (const int*)d_in[4];
  const float* W1        = (const float*)d_in[5];
  const float* b1        = (const float*)d_in[6];
  const float* gamma     = (const float*)d_in[7];
  const float* beta      = (const float*)d_in[8];
  const float* W2        = (const float*)d_in[9];
  const float* b2        = (const float*)d_in[10];
  const float* root_w    = (const float*)d_in[11];
  const float* bias      = (const float*)d_in[12];
  const float* Wc1       = (const float*)d_in[13];
  const float* bc1       = (const float*)d_in[14];
  const float* Wc2       = (const float*)d_in[15];
  const float* bc2       = (const float*)d_in[16];
  float* out = (float*)d_out;

  // ws layout (floats)
  float* wsf     = (float*)d_ws;
  float* wsS     = wsf;            // 256
  float* wsm     = wsf + 256;      // 16
  float* sc      = wsf + 272;      // 64
  float* sh      = wsf + 336;      // 64
  float* sums    = wsf + 400;      // 1280
  float* cnt     = wsf + 1680;     // 64
  unsigned* Bw1  = (unsigned*)(wsf + 1744);  // 1024 u32
  unsigned* Bbuf = (unsigned*)(wsf + 2768);  // 16896 u32
  float* aggr    = wsf + 19664;    // N*20 = 1,000,000 floats

  // zero the accumulator regions (S, m, sc, sh, sums, cnt)
  (void)hipMemsetAsync(d_ws, 0, 1744 * sizeof(float), stream);

  prep_kernel<<<1, 256, 0, stream>>>(W2, b2, W1, Bbuf, Bw1);
  stats_kernel<<<512, 256, 0, stream>>>(edge_attr, wsS, wsm);
  node_init_kernel<<<(N_NODES + 255) / 256, 256, 0, stream>>>(x, root_w, bias,
                                                              aggr);
  bn_kernel<<<1, 64, 0, stream>>>(wsS, wsm, W1, b1, gamma, beta, sc, sh);
  edge_kernel<<<512, 256, 0, stream>>>(x, edge_attr, ei, sc, sh, Bbuf, Bw1,
                                       aggr);
  pool_kernel<<<(N_NODES + 255) / 256, 256, 0, stream>>>(aggr, batch, sums,
                                                         cnt);
  critic_kernel<<<G_GRAPHS, 256, 0, stream>>>(sums, cnt, a, Wc1, bc1, Wc2, bc2,
                                              out);
}

// Round 3
// 381.864 us; speedup vs baseline: 1.9635x; 1.9635x over previous
//
#include <hip/hip_runtime.h>

// NNConvCritic on MI355X (gfx950).
// R3: remove ALL global atomics. aggr/out are never needed per-node (only
// per-graph sums feed the critic), so edge messages accumulate per-graph in
// LDS (batch[dst] gather) and flush once per block to a private gpart slice.
// x@root_w + bias folds in via per-graph x sums (linearity).
// Pipeline: memset -> prep -> stats -> bn -> sumx -> edge -> critic.

#define E_EDGES   800000
#define N_NODES   50000
#define G_GRAPHS  64
#define EDGE_GRID 512

typedef _Float16 f16x2 __attribute__((ext_vector_type(2)));
typedef _Float16 f16x8 __attribute__((ext_vector_type(8)));
typedef __fp16   fp16x2 __attribute__((ext_vector_type(2)));
typedef float    f32x4 __attribute__((ext_vector_type(4)));
typedef unsigned u32x4 __attribute__((ext_vector_type(4)));

union H2U { f16x2 h; unsigned u; };
union F8U { f16x8 v; f16x2 h2[4]; u32x4 u4; };

__device__ __forceinline__ f16x2 pkrtz(float a, float b) {
  fp16x2 r = __builtin_amdgcn_cvt_pkrtz(a, b);
  return __builtin_bit_cast(f16x2, r);
}

// ---------------------------------------------------------------------------
// prep: build f16 B-fragment tables (W2' for the main GEMM, W1 for h-GEMM,
// plus the b2 row-trick slot). Layouts documented in R0.
// ---------------------------------------------------------------------------
__global__ __launch_bounds__(256) void prep_kernel(
    const float* __restrict__ W2, const float* __restrict__ b2,
    const float* __restrict__ W1, unsigned* __restrict__ Bbuf,
    unsigned* __restrict__ Bw1)
{
  int tid = threadIdx.x;
  for (int idx = tid; idx < 33 * 512; idx += 256) {
    int r = idx & 3, lane = (idx >> 2) & 63, nt = (idx >> 8) & 1, s = idx >> 9;
    int q = lane >> 4, nl = lane & 15, n = nt * 16 + nl;
    float v0 = 0.f, v1 = 0.f;
    if (n < 20) {
      if (s < 32) {
        int K0 = s * 32 + q * 8 + 2 * r;
        int K1 = K0 + 1;
        v0 = W2[(K0 >> 4) * 320 + (K0 & 15) * 20 + n];
        v1 = W2[(K1 >> 4) * 320 + (K1 & 15) * 20 + n];
      } else if (q < 2) {
        int i0 = q * 8 + 2 * r;
        v0 = b2[i0 * 20 + n];
        v1 = b2[(i0 + 1) * 20 + n];
      }
    }
    H2U pk; pk.h = pkrtz(v0, v1);
    Bbuf[idx] = pk.u;
  }
  for (int idx = tid; idx < 1024; idx += 256) {
    int r = idx & 3, lane = (idx >> 2) & 63, nt = idx >> 8;
    int q = lane >> 4, nl = lane & 15, n = nt * 16 + nl;
    int k0 = q * 8 + 2 * r;
    float v0 = (k0 < 16)     ? W1[k0 * 64 + n]       : 0.f;
    float v1 = (k0 + 1 < 16) ? W1[(k0 + 1) * 64 + n] : 0.f;
    H2U pk; pk.h = pkrtz(v0, v1);
    Bw1[idx] = pk.u;
  }
}

// ---------------------------------------------------------------------------
// stats: S = EA^T EA (16x16) + column sums m, one pass, MFMA(a,a) trick.
// ---------------------------------------------------------------------------
__global__ __launch_bounds__(256) void stats_kernel(
    const float* __restrict__ ea, float* __restrict__ wsS,
    float* __restrict__ wsm)
{
  int lane = threadIdx.x & 63, wave = threadIdx.x >> 6;
  int nl = lane & 15, q = lane >> 4;
  int gw = blockIdx.x * 4 + wave;
  int stride = gridDim.x * 4;
  f32x4 acc = (f32x4){0.f, 0.f, 0.f, 0.f};
  float ms = 0.f;
  for (int c0 = gw; c0 < E_EDGES / 32; c0 += stride) {
    const float* p = ea + (size_t)(c0 * 32 + q * 8) * 16 + nl;
    float v0 = p[0],      v1 = p[16],     v2 = p[32],  v3 = p[48];
    float v4 = p[64],     v5 = p[80],     v6 = p[96],  v7 = p[112];
    ms += (v0 + v1) + (v2 + v3) + (v4 + v5) + (v6 + v7);
    F8U av;
    av.h2[0] = pkrtz(v0, v1); av.h2[1] = pkrtz(v2, v3);
    av.h2[2] = pkrtz(v4, v5); av.h2[3] = pkrtz(v6, v7);
    acc = __builtin_amdgcn_mfma_f32_16x16x32_f16(av.v, av.v, acc, 0, 0, 0);
  }
  ms += __shfl_xor(ms, 16, 64);
  ms += __shfl_xor(ms, 32, 64);
  if (q == 0) unsafeAtomicAdd(&wsm[nl], ms);
#pragma unroll
  for (int r = 0; r < 4; ++r)
    unsafeAtomicAdd(&wsS[(q * 4 + r) * 16 + nl], acc[r]);
}

// ---------------------------------------------------------------------------
// bn: per-channel scale/shift from moments (folds b1 into shift).
// ---------------------------------------------------------------------------
__global__ void bn_kernel(const float* __restrict__ wsS,
                          const float* __restrict__ wsm,
                          const float* __restrict__ W1,
                          const float* __restrict__ b1,
                          const float* __restrict__ gamma,
                          const float* __restrict__ beta,
                          float* __restrict__ sc, float* __restrict__ sh)
{
  int c = threadIdx.x;  // 64 threads
  float w[16];
#pragma unroll
  for (int j = 0; j < 16; ++j) w[j] = W1[j * 64 + c];
  const float invE = 1.0f / (float)E_EDGES;
  float mw = 0.f;
#pragma unroll
  for (int j = 0; j < 16; ++j) mw += wsm[j] * w[j];
  mw *= invE;
  float qf = 0.f;
  for (int j = 0; j < 16; ++j) {
    float t = 0.f;
#pragma unroll
    for (int j2 = 0; j2 < 16; ++j2) t += wsS[j * 16 + j2] * w[j2];
    qf += w[j] * t;
  }
  qf *= invE;
  float b = b1[c];
  float meanH = mw + b;
  float eh2 = qf + 2.f * b * mw + b * b;
  float var = eh2 - meanH * meanH;
  float s = gamma[c] * rsqrtf(var + 1e-5f);
  sc[c] = s;
  sh[c] = beta[c] + (b - meanH) * s;
}

// ---------------------------------------------------------------------------
// sumx: per-graph x column sums + node count (batch is sorted -> binary
// search the segment). One block per graph.
// ---------------------------------------------------------------------------
__global__ __launch_bounds__(256) void sumx_kernel(
    const float* __restrict__ x, const int* __restrict__ batch,
    float* __restrict__ sumx, float* __restrict__ cntf)
{
  int g = blockIdx.x, t = threadIdx.x;
  __shared__ int se[2];
  if (t == 0 || t == 1) {
    int key = g + t;  // lower_bound(g), lower_bound(g+1)
    int lo = 0, hi = N_NODES;
    while (lo < hi) {
      int mid = (lo + hi) >> 1;
      if (batch[mid] < key) lo = mid + 1; else hi = mid;
    }
    se[t] = lo;
  }
  __syncthreads();
  int start = se[0], end = se[1];
  int c = t & 15, rr = t >> 4;  // 16 cols x 16 row groups
  float s = 0.f;
  for (int n = start + rr; n < end; n += 16) s += x[(size_t)n * 16 + c];
  __shared__ float red[256];
  red[t] = s;
  __syncthreads();
#pragma unroll
  for (int st = 128; st >= 16; st >>= 1) {
    if (t < st) red[t] += red[t + st];
    __syncthreads();
  }
  if (t < 16) sumx[g * 16 + t] = red[t];
  if (t == 0) cntf[g] = (float)(end - start);
}

// ---------------------------------------------------------------------------
// edge_kernel: msg = (h ⊗ x) @ W2' via f16 MFMA (K=1024 + b2 trick), then
// per-graph LDS accumulation (batch[dst] gather, ds_add_f32), one flush to
// gpart[block][1280] at the end. No global atomics.
// ---------------------------------------------------------------------------
__global__ __launch_bounds__(256, 2) void edge_kernel(
    const float* __restrict__ x, const float* __restrict__ ea,
    const int* __restrict__ ei, const int* __restrict__ batch,
    const float* __restrict__ sc, const float* __restrict__ sh,
    const unsigned* __restrict__ Bbuf, const unsigned* __restrict__ Bw1v,
    float* __restrict__ gpart)
{
  __shared__ unsigned hh[4 * 64 * 17];   // [tile][channel][m(16) pad 17]
  __shared__ float msgbuf[4 * 1280];     // per-wave [64 edges][20]
  __shared__ float gacc[G_GRAPHS * 20];  // per-graph running sums
  __shared__ int gq[64];                 // graph of each edge in the tile
  const int tid = threadIdx.x;
  const int lane = tid & 63, wave = tid >> 6;
  const int nl = lane & 15, q = lane >> 4;
  const int* srcp = ei;
  const int* dstp = ei + E_EDGES;

  for (int v = tid; v < G_GRAPHS * 20; v += 256) gacc[v] = 0.f;

  // B fragments for this wave's K-quarter: s in [8*wave, 8*wave+8)
  F8U bb[8][2];
#pragma unroll
  for (int sl = 0; sl < 8; ++sl)
#pragma unroll
    for (int nt = 0; nt < 2; ++nt)
      bb[sl][nt].u4 =
          ((const u32x4*)Bbuf)[((wave * 8 + sl) * 2 + nt) * 64 + lane];
  F8U bx[2];
  if (wave == 3) {
    bx[0].u4 = ((const u32x4*)Bbuf)[(32 * 2 + 0) * 64 + lane];
    bx[1].u4 = ((const u32x4*)Bbuf)[(32 * 2 + 1) * 64 + lane];
  }
  F8U bw1[4];
#pragma unroll
  for (int nt = 0; nt < 4; ++nt)
    bw1[nt].u4 = ((const u32x4*)Bw1v)[nt * 64 + lane];
  float scv[4], shv[4];
#pragma unroll
  for (int nt = 0; nt < 4; ++nt) {
    scv[nt] = sc[nt * 16 + nl];
    shv[nt] = sh[nt * 16 + nl];
  }
  const int hbase = (16 * wave + (q >> 1)) * 17 + nl;
  const int i0 = (q & 1) * 8;
  __syncthreads();  // gacc init visible

  for (int it = blockIdx.x; it < (E_EDGES / 64); it += gridDim.x) {
    const int base = it * 64;

    // ---- h-stage: wave computes h for its own 16-edge tile ----
    {
      const int e = base + wave * 16 + nl;
      F8U aEA;
      if (q < 2) {
        const float* p = ea + (size_t)e * 16 + q * 8;
        f32x4 u = *(const f32x4*)p;
        f32x4 v = *(const f32x4*)(p + 4);
        aEA.h2[0] = pkrtz(u[0], u[1]); aEA.h2[1] = pkrtz(u[2], u[3]);
        aEA.h2[2] = pkrtz(v[0], v[1]); aEA.h2[3] = pkrtz(v[2], v[3]);
      } else {
        aEA.u4 = (u32x4){0u, 0u, 0u, 0u};
      }
#pragma unroll
      for (int nt = 0; nt < 4; ++nt) {
        f32x4 hD = __builtin_amdgcn_mfma_f32_16x16x32_f16(
            aEA.v, bw1[nt].v, (f32x4){0.f, 0.f, 0.f, 0.f}, 0, 0, 0);
#pragma unroll
        for (int r = 0; r < 4; ++r) {
          float h = fmaxf(hD[r] * scv[nt] + shv[nt], 0.f);
          H2U pk; pk.h = pkrtz(h, h);  // packed-duplicated
          hh[(wave * 64 + nt * 16 + nl) * 17 + q * 4 + r] = pk.u;
        }
      }
    }

    // ---- x gather (registers, f16 packed); wave0 also resolves edge->graph
    F8U xp[4];
#pragma unroll
    for (int t = 0; t < 4; ++t) {
      int srcT = srcp[base + t * 16 + nl];
      const float* p = x + (size_t)srcT * 16 + i0;
      f32x4 u = *(const f32x4*)p;
      f32x4 v = *(const f32x4*)(p + 4);
      xp[t].h2[0] = pkrtz(u[0], u[1]); xp[t].h2[1] = pkrtz(u[2], u[3]);
      xp[t].h2[2] = pkrtz(v[0], v[1]); xp[t].h2[3] = pkrtz(v[2], v[3]);
    }
    if (wave == 0) gq[lane] = batch[dstp[base + lane]];
    __syncthreads();

    // ---- main K-loop: A[m][K] = h[m][K>>4] * x[m][K&15] ----
    f32x4 acc[4][2];
#pragma unroll
    for (int t = 0; t < 4; ++t) {
      acc[t][0] = (f32x4){0.f, 0.f, 0.f, 0.f};
      acc[t][1] = (f32x4){0.f, 0.f, 0.f, 0.f};
    }
#pragma unroll
    for (int sl = 0; sl < 8; ++sl) {
#pragma unroll
      for (int t = 0; t < 4; ++t) {
        H2U hu; hu.u = hh[hbase + t * 1088 + sl * 34];
        F8U av;
        av.h2[0] = hu.h * xp[t].h2[0];
        av.h2[1] = hu.h * xp[t].h2[1];
        av.h2[2] = hu.h * xp[t].h2[2];
        av.h2[3] = hu.h * xp[t].h2[3];
        acc[t][0] = __builtin_amdgcn_mfma_f32_16x16x32_f16(
            av.v, bb[sl][0].v, acc[t][0], 0, 0, 0);
        acc[t][1] = __builtin_amdgcn_mfma_f32_16x16x32_f16(
            av.v, bb[sl][1].v, acc[t][1], 0, 0, 0);
      }
    }
    if (wave == 3) {  // b2 extra K-step: A = x (coefficient-1 trick)
#pragma unroll
      for (int t = 0; t < 4; ++t) {
        F8U av;
        if (q < 2) av = xp[t];
        else       av.u4 = (u32x4){0u, 0u, 0u, 0u};
        acc[t][0] = __builtin_amdgcn_mfma_f32_16x16x32_f16(
            av.v, bx[0].v, acc[t][0], 0, 0, 0);
        acc[t][1] = __builtin_amdgcn_mfma_f32_16x16x32_f16(
            av.v, bx[1].v, acc[t][1], 0, 0, 0);
      }
    }

    // ---- per-wave msg slices (C/D layout: col = nl, row = q*4+r) ----
    float* ms = msgbuf + wave * 1280;
#pragma unroll
    for (int t = 0; t < 4; ++t) {
#pragma unroll
      for (int r = 0; r < 4; ++r)
        ms[(t * 16 + q * 4 + r) * 20 + nl] = acc[t][0][r];
      if (nl < 4) {
#pragma unroll
        for (int r = 0; r < 4; ++r)
          ms[(t * 16 + q * 4 + r) * 20 + 16 + nl] = acc[t][1][r];
      }
    }
    __syncthreads();

    // ---- accumulate into per-graph LDS sums (ds_add_f32) ----
#pragma unroll
    for (int k2 = 0; k2 < 5; ++k2) {
      int v = tid + k2 * 256;
      int edl = v / 20, o = v - edl * 20;
      float val = msgbuf[v] + msgbuf[1280 + v] + msgbuf[2560 + v] +
                  msgbuf[3840 + v];
      atomicAdd(&gacc[gq[edl] * 20 + o], val);
    }
    __syncthreads();
  }

  // ---- one flush per block: private gpart slice, plain stores ----
  __syncthreads();
  float* gp = gpart + (size_t)blockIdx.x * (G_GRAPHS * 20);
  for (int v = tid; v < G_GRAPHS * 20; v += 256) gp[v] = gacc[v];
}

// ---------------------------------------------------------------------------
// critic: block per graph. Reduce gpart slices, form pooled =
// (msgsum + sumx@root_w + cnt*bias)/max(cnt,1), then the 2-layer MLP.
// ---------------------------------------------------------------------------
__global__ __launch_bounds__(256) void critic_kernel(
    const float* __restrict__ gpart, const float* __restrict__ sumx,
    const float* __restrict__ cntf, const float* __restrict__ root_w,
    const float* __restrict__ bias, const float* __restrict__ a,
    const float* __restrict__ Wc1, const float* __restrict__ bc1,
    const float* __restrict__ Wc2, const float* __restrict__ bc2,
    float* __restrict__ out)
{
  int g = blockIdx.x, t = threadIdx.x;
  __shared__ float part[240];
  __shared__ float pooled[20];
  if (t < 240) {
    int col = t % 20, r = t / 20;  // 12 row groups
    float s = 0.f;
    for (int sl = r; sl < EDGE_GRID; sl += 12)
      s += gpart[(size_t)sl * (G_GRAPHS * 20) + g * 20 + col];
    part[t] = s;
  }
  __syncthreads();
  if (t < 20) {
    float s = 0.f;
#pragma unroll
    for (int r = 0; r < 12; ++r) s += part[r * 20 + t];
    float cnt = cntf[g];
    float base = bias[t] * cnt;
#pragma unroll
    for (int i = 0; i < 16; ++i) base += sumx[g * 16 + i] * root_w[i * 20 + t];
    pooled[t] = (s + base) / fmaxf(cnt, 1.f);
  }
  __syncthreads();
  float z = bc1[t];
#pragma unroll
  for (int j = 0; j < 20; ++j) z += pooled[j] * Wc1[j * 256 + t];
#pragma unroll
  for (int j = 0; j < 8; ++j) z += a[g * 8 + j] * Wc1[(20 + j) * 256 + t];
  z = fmaxf(z, 0.f);
  float p = z * Wc2[t];
#pragma unroll
  for (int off = 32; off >= 1; off >>= 1) p += __shfl_down(p, off, 64);
  __shared__ float red[4];
  if ((t & 63) == 0) red[t >> 6] = p;
  __syncthreads();
  if (t == 0) out[g] = red[0] + red[1] + red[2] + red[3] + bc2[0];
}

// ---------------------------------------------------------------------------
extern "C" void kernel_launch(void* const* d_in, const int* in_sizes, int n_in,
                              void* d_out, int out_size, void* d_ws,
                              size_t ws_size, hipStream_t stream) {
  const float* x         = (const float*)d_in[0];
  const float* edge_attr = (const float*)d_in[1];
  const float* a         = (const float*)d_in[2];
  const int*   ei        = (const int*)d_in[3];
  const int*   batch     = (const int*)d_in[4];
  const float* W1        = (const float*)d_in[5];
  const float* b1        = (const float*)d_in[6];
  const float* gamma     = (const float*)d_in[7];
  const float* beta      = (const float*)d_in[8];
  const float* W2        = (const float*)d_in[9];
  const float* b2        = (const float*)d_in[10];
  const float* root_w    = (const float*)d_in[11];
  const float* bias      = (const float*)d_in[12];
  const float* Wc1       = (const float*)d_in[13];
  const float* bc1       = (const float*)d_in[14];
  const float* Wc2       = (const float*)d_in[15];
  const float* bc2       = (const float*)d_in[16];
  float* out = (float*)d_out;

  // ws layout (floats)
  float* wsf     = (float*)d_ws;
  float* wsS     = wsf;            // 256
  float* wsm     = wsf + 256;      // 16
  float* sc      = wsf + 272;      // 64
  float* sh      = wsf + 336;      // 64
  float* sumx    = wsf + 400;      // 64*16 = 1024
  float* cntf    = wsf + 1424;     // 64
  unsigned* Bw1  = (unsigned*)(wsf + 1488);  // 1024 u32
  unsigned* Bbuf = (unsigned*)(wsf + 2512);  // 16896 u32
  float* gpart   = wsf + 19408;    // EDGE_GRID*1280 = 655360

  // zero the MFMA-stats accumulators (wsS, wsm)
  (void)hipMemsetAsync(d_ws, 0, 272 * sizeof(float), stream);

  prep_kernel<<<1, 256, 0, stream>>>(W2, b2, W1, Bbuf, Bw1);
  stats_kernel<<<512, 256, 0, stream>>>(edge_attr, wsS, wsm);
  bn_kernel<<<1, 64, 0, stream>>>(wsS, wsm, W1, b1, gamma, beta, sc, sh);
  sumx_kernel<<<G_GRAPHS, 256, 0, stream>>>(x, batch, sumx, cntf);
  edge_kernel<<<EDGE_GRID, 256, 0, stream>>>(x, edge_attr, ei, batch, sc, sh,
                                             Bbuf, Bw1, gpart);
  critic_kernel<<<G_GRAPHS, 256, 0, stream>>>(gpart, sumx, cntf, root_w, bias,
                                              a, Wc1, bc1, Wc2, bc2, out);
}